// Round 1
// baseline (449.657 us; speedup 1.0000x reference)
//
#include <hip/hip_runtime.h>

// GatedMoE on MI355X (gfx950), fp16 MFMA path.
// Pipeline: cvt(x,W1^T,W2^T -> fp16) -> router -> capacity scan -> GEMM1+SwiGLU -> GEMM2 -> weighted gather.
// All scratch in d_ws (~155 MB). No host sync / malloc (graph-capture safe).

typedef _Float16 half8 __attribute__((ext_vector_type(8)));
typedef _Float16 half4t __attribute__((ext_vector_type(4)));
typedef float f4 __attribute__((ext_vector_type(4)));

#define N_TOK 4096
#define DDIM  768
#define HDIM  2048
#define NEXP  8
#define CAP   614   // int(1.2 * 4096 / 8)
#define CAPP  640   // capacity padded to 10 tiles of 64

// ---- workspace layout (bytes) ----
#define XH_OFF    0L           // (4097*768) fp16           = 6,292,992
#define W1T_OFF   6292992L     // [8][4096][768] fp16       = 50,331,648
#define W2T_OFF   56624640L    // [8][768][2048] fp16       = 25,165,824
#define ACT_OFF   81790464L    // [16][640][2048] fp16      = 41,943,040
#define YBUF_OFF  123733504L   // [16][640][768] fp32       = 31,457,280
#define EIDX_OFF  155190784L   // [4096][2] int
#define WTS_OFF   155223552L   // [4096][2] float
#define TOKL_OFF  155256320L   // [16][640] int
#define TOKP_OFF  155297280L   // [2][4096] int
#define CNT_OFF   155330048L   // [16] int

// -------------------- conversions --------------------

__global__ __launch_bounds__(256) void cvt_x_kernel(const float* __restrict__ x,
                                                    _Float16* __restrict__ xh) {
  long i = (long)blockIdx.x * 256 + threadIdx.x;
  long base = i * 4;
  const long total = (long)(N_TOK + 1) * DDIM;  // includes zero pad row (token id 4096)
  if (base >= total) return;
  half4t hv;
  if (base < (long)N_TOK * DDIM) {
    f4 v = *(const f4*)(x + base);
    hv[0] = (_Float16)v[0]; hv[1] = (_Float16)v[1];
    hv[2] = (_Float16)v[2]; hv[3] = (_Float16)v[3];
  } else {
    hv[0] = hv[1] = hv[2] = hv[3] = (_Float16)0.f;
  }
  *(half4t*)(xh + base) = hv;
}

// transpose+convert: src fp32 [e][R][C] -> dst fp16 [e][C][R]
__global__ __launch_bounds__(256) void cvt_tr_kernel(const float* __restrict__ src,
                                                     _Float16* __restrict__ dst,
                                                     int R, int C) {
  __shared__ float tile[32][33];  // +1 pad: conflict-free transpose
  int e = blockIdx.z;
  int r0 = blockIdx.x * 32, c0 = blockIdx.y * 32;
  long sb = (long)e * R * C;
  int t = threadIdx.x;
  int tr = t >> 5, tc = t & 31;
#pragma unroll
  for (int i = 0; i < 4; i++)
    tile[tr + i * 8][tc] = src[sb + (long)(r0 + tr + i * 8) * C + c0 + tc];
  __syncthreads();
#pragma unroll
  for (int i = 0; i < 4; i++)
    dst[sb + (long)(c0 + tr + i * 8) * R + r0 + tc] = (_Float16)tile[tc][tr + i * 8];
}

// -------------------- router --------------------
// one wave per token; Wg (768x8) in LDS; shuffle-reduce 8 logits; top-2 + softmax.
__global__ __launch_bounds__(256) void router_kernel(const float* __restrict__ x,
                                                     const float* __restrict__ Wg,
                                                     int* __restrict__ eidx,
                                                     float* __restrict__ wts) {
  __shared__ float wg[DDIM * NEXP];  // 24 KB
  int t = threadIdx.x;
  for (int i = t; i < DDIM * NEXP; i += 256) wg[i] = Wg[i];
  __syncthreads();
  int w = t >> 6, lane = t & 63;
  int tok = blockIdx.x * 4 + w;
  float acc[8] = {0.f, 0.f, 0.f, 0.f, 0.f, 0.f, 0.f, 0.f};
  const float* xr = x + (long)tok * DDIM;
#pragma unroll
  for (int i = 0; i < 12; i++) {
    float xv = xr[i * 64 + lane];
    const float* wr = &wg[(i * 64 + lane) * 8];
#pragma unroll
    for (int e2 = 0; e2 < 8; e2++) acc[e2] += xv * wr[e2];
  }
#pragma unroll
  for (int e2 = 0; e2 < 8; e2++) {
    float v = acc[e2];
    v += __shfl_xor(v, 32); v += __shfl_xor(v, 16); v += __shfl_xor(v, 8);
    v += __shfl_xor(v, 4);  v += __shfl_xor(v, 2);  v += __shfl_xor(v, 1);
    acc[e2] = v;
  }
  if (lane == 0) {
    // top-2, ties -> earliest index (matches jax.lax.top_k)
    float m0 = -1e30f; int i0 = 0;
#pragma unroll
    for (int e2 = 0; e2 < 8; e2++) if (acc[e2] > m0) { m0 = acc[e2]; i0 = e2; }
    float m1 = -1e30f; int i1 = 0;
#pragma unroll
    for (int e2 = 0; e2 < 8; e2++) if (e2 != i0 && acc[e2] > m1) { m1 = acc[e2]; i1 = e2; }
    float tt = __expf(m1 - m0);          // <= 1
    float w0 = 1.f / (1.f + tt);
    eidx[tok * 2 + 0] = i0; eidx[tok * 2 + 1] = i1;
    wts[tok * 2 + 0] = w0;  wts[tok * 2 + 1] = 1.f - w0;
  }
}

// -------------------- capacity scan --------------------
// 16 waves, wave (k,e): ordered scan of 4096 tokens via ballot prefix -> positions
// exactly matching the reference cumsum/drop semantics.
__global__ __launch_bounds__(1024) void scan_kernel(const int* __restrict__ eidx,
                                                    int* __restrict__ toklist,
                                                    int* __restrict__ tokpos,
                                                    int* __restrict__ counts) {
  int t = threadIdx.x;
  int wid = t >> 6, lane = t & 63;
  int k = wid >> 3, e = wid & 7;
  int z = k * 8 + e;
  int base = 0;
  for (int n0 = 0; n0 < N_TOK; n0 += 64) {
    int n = n0 + lane;
    bool pred = (eidx[n * 2 + k] == e);
    unsigned long long mask = __ballot(pred);
    if (pred) {
      int pos = base + __popcll(mask & ((1ull << lane) - 1ull));
      if (pos < CAP) {
        toklist[z * CAPP + pos] = n;
        tokpos[k * N_TOK + n] = z * CAPP + pos;
      } else {
        tokpos[k * N_TOK + n] = -1;  // dropped
      }
    }
    base += __popcll(mask);
  }
  if (lane == 0) counts[z] = (base < CAP) ? base : CAP;
}

// -------------------- GEMM1 + fused SwiGLU --------------------
// act[z][m][n] = h1 * silu(h2), h = Xg[m,:] @ W1e ; block tile 64 rows x 64 act cols
// (h-tile 64x128: cols n0..n0+63 and 2048+n0..). Wave w owns matching h1/h2 col
// strips (w*16) so the GLU is register-local in the MFMA C layout.
// LDS: XOR-swizzled 16B units -> conflict-free ds_read_b128/ds_write_b128.
__global__ __launch_bounds__(256) void gemm1_kernel(const _Float16* __restrict__ xh,
                                                    const _Float16* __restrict__ w1t,
                                                    const int* __restrict__ toklist,
                                                    const int* __restrict__ counts,
                                                    _Float16* __restrict__ act) {
  int z = blockIdx.z;
  int e = z & 7;
  int count = counts[z];
  int m0 = blockIdx.x * 64;
  if (m0 >= count) return;
  int n0 = blockIdx.y * 64;

  __shared__ half8 As[64][4];    // [row][unit^swz]
  __shared__ half8 Bs[128][4];   // rows 0..63: h1 cols, 64..127: h2 cols
  __shared__ int toks[64];

  int t = threadIdx.x;
  if (t < 64) {
    int r = m0 + t;
    toks[t] = (r < count) ? toklist[z * CAPP + r] : N_TOK;  // pad -> zero row
  }
  __syncthreads();

  int lane = t & 63, w = t >> 6, q = lane >> 4, m16 = lane & 15;
  int srow = t >> 2, su = t & 3;
  int sphys = su ^ ((srow >> 1) & 3);   // swz(64+r) == swz(r)
  const _Float16* aptr  = xh + (long)toks[srow] * DDIM + su * 8;
  const _Float16* b1ptr = w1t + ((long)e * 4096 + n0 + srow) * DDIM + su * 8;
  const _Float16* b2ptr = b1ptr + (long)HDIM * DDIM;

  f4 zero4 = {0.f, 0.f, 0.f, 0.f};
  f4 acc[4][2];
#pragma unroll
  for (int i = 0; i < 4; i++) { acc[i][0] = zero4; acc[i][1] = zero4; }

  for (int kk = 0; kk < DDIM; kk += 32) {
    half8 av = *(const half8*)(aptr + kk);
    half8 b1 = *(const half8*)(b1ptr + kk);
    half8 b2 = *(const half8*)(b2ptr + kk);
    __syncthreads();
    As[srow][sphys] = av;
    Bs[srow][sphys] = b1;
    Bs[64 + srow][sphys] = b2;
    __syncthreads();
    half8 bf0, bf1;
    {
      int c0 = w * 16 + m16;
      bf0 = Bs[c0][q ^ ((c0 >> 1) & 3)];
      int c1 = 64 + w * 16 + m16;
      bf1 = Bs[c1][q ^ ((c1 >> 1) & 3)];
    }
#pragma unroll
    for (int rt = 0; rt < 4; rt++) {
      int row = rt * 16 + m16;
      half8 a = As[row][q ^ ((row >> 1) & 3)];
      acc[rt][0] = __builtin_amdgcn_mfma_f32_16x16x32_f16(a, bf0, acc[rt][0], 0, 0, 0);
      acc[rt][1] = __builtin_amdgcn_mfma_f32_16x16x32_f16(a, bf1, acc[rt][1], 0, 0, 0);
    }
  }

  long ab = (long)z * CAPP * HDIM;
#pragma unroll
  for (int rt = 0; rt < 4; rt++) {
#pragma unroll
    for (int r = 0; r < 4; r++) {
      int row = m0 + rt * 16 + q * 4 + r;   // C/D: row = quad*4 + reg
      int col = n0 + w * 16 + m16;          //      col = lane&15
      float h1 = acc[rt][0][r], h2 = acc[rt][1][r];
      float s = h2 / (1.f + __expf(-h2));   // silu(h2)
      act[ab + (long)row * HDIM + col] = (_Float16)(h1 * s);
    }
  }
}

// -------------------- GEMM2 --------------------
// ye[z][m][d] = act[z][m,:] @ W2e ; block tile 64 rows x 128 cols; wave w owns
// col strips w*16 and 64+w*16.
__global__ __launch_bounds__(256) void gemm2_kernel(const _Float16* __restrict__ act,
                                                    const _Float16* __restrict__ w2t,
                                                    const int* __restrict__ counts,
                                                    float* __restrict__ ybuf) {
  int z = blockIdx.z;
  int e = z & 7;
  int count = counts[z];
  int m0 = blockIdx.x * 64;
  if (m0 >= count) return;
  int n0 = blockIdx.y * 128;

  __shared__ half8 As[64][4];
  __shared__ half8 Bs[128][4];

  int t = threadIdx.x;
  int lane = t & 63, w = t >> 6, q = lane >> 4, m16 = lane & 15;
  int srow = t >> 2, su = t & 3;
  int sphys = su ^ ((srow >> 1) & 3);
  const _Float16* aptr  = act + (long)z * CAPP * HDIM + (long)(m0 + srow) * HDIM + su * 8;
  const _Float16* b1ptr = w2t + ((long)e * DDIM + n0 + srow) * HDIM + su * 8;
  const _Float16* b2ptr = b1ptr + 64L * HDIM;

  f4 zero4 = {0.f, 0.f, 0.f, 0.f};
  f4 acc[4][2];
#pragma unroll
  for (int i = 0; i < 4; i++) { acc[i][0] = zero4; acc[i][1] = zero4; }

  for (int kk = 0; kk < HDIM; kk += 32) {
    half8 av = *(const half8*)(aptr + kk);
    half8 b1 = *(const half8*)(b1ptr + kk);
    half8 b2 = *(const half8*)(b2ptr + kk);
    __syncthreads();
    As[srow][sphys] = av;
    Bs[srow][sphys] = b1;
    Bs[64 + srow][sphys] = b2;
    __syncthreads();
    half8 bf0, bf1;
    {
      int c0 = w * 16 + m16;
      bf0 = Bs[c0][q ^ ((c0 >> 1) & 3)];
      int c1 = 64 + w * 16 + m16;
      bf1 = Bs[c1][q ^ ((c1 >> 1) & 3)];
    }
#pragma unroll
    for (int rt = 0; rt < 4; rt++) {
      int row = rt * 16 + m16;
      half8 a = As[row][q ^ ((row >> 1) & 3)];
      acc[rt][0] = __builtin_amdgcn_mfma_f32_16x16x32_f16(a, bf0, acc[rt][0], 0, 0, 0);
      acc[rt][1] = __builtin_amdgcn_mfma_f32_16x16x32_f16(a, bf1, acc[rt][1], 0, 0, 0);
    }
  }

  long yb = (long)z * CAPP * DDIM;
#pragma unroll
  for (int rt = 0; rt < 4; rt++) {
#pragma unroll
    for (int hh = 0; hh < 2; hh++) {
#pragma unroll
      for (int r = 0; r < 4; r++) {
        int row = m0 + rt * 16 + q * 4 + r;
        int col = n0 + hh * 64 + w * 16 + m16;
        ybuf[yb + (long)row * DDIM + col] = acc[rt][hh][r];
      }
    }
  }
}

// -------------------- gather --------------------
// out[n,:] = sum_k w_k * ybuf[tokpos[k][n], :]  (0 contributions for dropped)
__global__ __launch_bounds__(256) void gather_kernel(const float* __restrict__ ybuf,
                                                     const int* __restrict__ tokpos,
                                                     const float* __restrict__ wts,
                                                     float* __restrict__ out) {
  int gid = blockIdx.x * 256 + threadIdx.x;  // < 4096*192
  int row = gid / 192, seg = gid % 192;
  f4 o = {0.f, 0.f, 0.f, 0.f};
#pragma unroll
  for (int k = 0; k < 2; k++) {
    int p = tokpos[k * N_TOK + row];
    if (p >= 0) {
      float wv = wts[row * 2 + k];
      f4 y = *(const f4*)(ybuf + (long)p * DDIM + seg * 4);
      o[0] += wv * y[0]; o[1] += wv * y[1]; o[2] += wv * y[2]; o[3] += wv * y[3];
    }
  }
  *(f4*)(out + (long)row * DDIM + seg * 4) = o;
}

// -------------------- launch --------------------

extern "C" void kernel_launch(void* const* d_in, const int* in_sizes, int n_in,
                              void* d_out, int out_size, void* d_ws, size_t ws_size,
                              hipStream_t stream) {
  const float* x  = (const float*)d_in[0];
  const float* Wg = (const float*)d_in[1];
  const float* W1 = (const float*)d_in[2];
  const float* W2 = (const float*)d_in[3];
  float* out = (float*)d_out;
  char* ws = (char*)d_ws;

  _Float16* xh   = (_Float16*)(ws + XH_OFF);
  _Float16* w1t  = (_Float16*)(ws + W1T_OFF);
  _Float16* w2t  = (_Float16*)(ws + W2T_OFF);
  _Float16* actb = (_Float16*)(ws + ACT_OFF);
  float* ybuf    = (float*)(ws + YBUF_OFF);
  int* eidx      = (int*)(ws + EIDX_OFF);
  float* wts     = (float*)(ws + WTS_OFF);
  int* toklist   = (int*)(ws + TOKL_OFF);
  int* tokpos    = (int*)(ws + TOKP_OFF);
  int* counts    = (int*)(ws + CNT_OFF);

  cvt_x_kernel<<<3073, 256, 0, stream>>>(x, xh);
  cvt_tr_kernel<<<dim3(24, 128, 8), 256, 0, stream>>>(W1, w1t, 768, 4096);
  cvt_tr_kernel<<<dim3(64, 24, 8), 256, 0, stream>>>(W2, w2t, 2048, 768);
  router_kernel<<<1024, 256, 0, stream>>>(x, Wg, eidx, wts);
  scan_kernel<<<1, 1024, 0, stream>>>(eidx, toklist, tokpos, counts);
  gemm1_kernel<<<dim3(10, 32, 16), 256, 0, stream>>>(xh, w1t, toklist, counts, actb);
  gemm2_kernel<<<dim3(10, 6, 16), 256, 0, stream>>>(actb, w2t, counts, ybuf);
  gather_kernel<<<3072, 256, 0, stream>>>(ybuf, tokpos, wts, out);
}

// Round 2
// 394.558 us; speedup vs baseline: 1.1396x; 1.1396x over previous
//
#include <hip/hip_runtime.h>

// GatedMoE on MI355X (gfx950), fp16 MFMA path, round 2.
// Changes vs r1: 128x128 GEMM tiles, global_load_lds(16B) staging with
// global-side swizzle permutation, XCD-affinity grid flattening (expert e -> XCD e),
// batched-load scan kernel.

typedef _Float16 half8 __attribute__((ext_vector_type(8)));
typedef _Float16 half4t __attribute__((ext_vector_type(4)));
typedef float f4 __attribute__((ext_vector_type(4)));

#define N_TOK 4096
#define DDIM  768
#define HDIM  2048
#define NEXP  8
#define CAP   614   // int(1.2 * 4096 / 8)
#define CAPP  640   // capacity padded to tiles

// ---- workspace layout (bytes) ----
#define XH_OFF    0L           // (4097*768) fp16           = 6,292,992
#define W1T_OFF   6292992L     // [8][4096][768] fp16       = 50,331,648
#define W2T_OFF   56624640L    // [8][768][2048] fp16       = 25,165,824
#define ACT_OFF   81790464L    // [16][640][2048] fp16      = 41,943,040
#define YBUF_OFF  123733504L   // [16][640][768] fp32       = 31,457,280
#define EIDX_OFF  155190784L   // [4096][2] int
#define WTS_OFF   155223552L   // [4096][2] float
#define TOKL_OFF  155256320L   // [16][640] int
#define TOKP_OFF  155297280L   // [2][4096] int
#define CNT_OFF   155330048L   // [16] int

// async 16B global->LDS copy. LDS side must be wave-uniform base + lane*16.
__device__ __forceinline__ void gld16(const void* g, void* l) {
  __builtin_amdgcn_global_load_lds(
      (const __attribute__((address_space(1))) unsigned int*)g,
      (__attribute__((address_space(3))) unsigned int*)l, 16, 0, 0);
}

// -------------------- conversions --------------------

__global__ __launch_bounds__(256) void cvt_x_kernel(const float* __restrict__ x,
                                                    _Float16* __restrict__ xh) {
  long i = (long)blockIdx.x * 256 + threadIdx.x;
  long base = i * 4;
  const long total = (long)(N_TOK + 1) * DDIM;  // includes zero pad row (token id 4096)
  if (base >= total) return;
  half4t hv;
  if (base < (long)N_TOK * DDIM) {
    f4 v = *(const f4*)(x + base);
    hv[0] = (_Float16)v[0]; hv[1] = (_Float16)v[1];
    hv[2] = (_Float16)v[2]; hv[3] = (_Float16)v[3];
  } else {
    hv[0] = hv[1] = hv[2] = hv[3] = (_Float16)0.f;
  }
  *(half4t*)(xh + base) = hv;
}

// transpose+convert: src fp32 [e][R][C] -> dst fp16 [e][C][R]
__global__ __launch_bounds__(256) void cvt_tr_kernel(const float* __restrict__ src,
                                                     _Float16* __restrict__ dst,
                                                     int R, int C) {
  __shared__ float tile[32][33];
  int e = blockIdx.z;
  int r0 = blockIdx.x * 32, c0 = blockIdx.y * 32;
  long sb = (long)e * R * C;
  int t = threadIdx.x;
  int tr = t >> 5, tc = t & 31;
#pragma unroll
  for (int i = 0; i < 4; i++)
    tile[tr + i * 8][tc] = src[sb + (long)(r0 + tr + i * 8) * C + c0 + tc];
  __syncthreads();
#pragma unroll
  for (int i = 0; i < 4; i++)
    dst[sb + (long)(c0 + tr + i * 8) * R + r0 + tc] = (_Float16)tile[tc][tr + i * 8];
}

// -------------------- router --------------------
__global__ __launch_bounds__(256) void router_kernel(const float* __restrict__ x,
                                                     const float* __restrict__ Wg,
                                                     int* __restrict__ eidx,
                                                     float* __restrict__ wts) {
  __shared__ float wg[DDIM * NEXP];  // 24 KB
  int t = threadIdx.x;
  for (int i = t; i < DDIM * NEXP; i += 256) wg[i] = Wg[i];
  __syncthreads();
  int w = t >> 6, lane = t & 63;
  int tok = blockIdx.x * 4 + w;
  float acc[8] = {0.f, 0.f, 0.f, 0.f, 0.f, 0.f, 0.f, 0.f};
  const float* xr = x + (long)tok * DDIM;
#pragma unroll
  for (int i = 0; i < 12; i++) {
    float xv = xr[i * 64 + lane];
    const float* wr = &wg[(i * 64 + lane) * 8];
#pragma unroll
    for (int e2 = 0; e2 < 8; e2++) acc[e2] += xv * wr[e2];
  }
#pragma unroll
  for (int e2 = 0; e2 < 8; e2++) {
    float v = acc[e2];
    v += __shfl_xor(v, 32); v += __shfl_xor(v, 16); v += __shfl_xor(v, 8);
    v += __shfl_xor(v, 4);  v += __shfl_xor(v, 2);  v += __shfl_xor(v, 1);
    acc[e2] = v;
  }
  if (lane == 0) {
    float m0 = -1e30f; int i0 = 0;
#pragma unroll
    for (int e2 = 0; e2 < 8; e2++) if (acc[e2] > m0) { m0 = acc[e2]; i0 = e2; }
    float m1 = -1e30f; int i1 = 0;
#pragma unroll
    for (int e2 = 0; e2 < 8; e2++) if (e2 != i0 && acc[e2] > m1) { m1 = acc[e2]; i1 = e2; }
    float tt = __expf(m1 - m0);
    float w0 = 1.f / (1.f + tt);
    eidx[tok * 2 + 0] = i0; eidx[tok * 2 + 1] = i1;
    wts[tok * 2 + 0] = w0;  wts[tok * 2 + 1] = 1.f - w0;
  }
}

// -------------------- capacity scan --------------------
// 16 waves, wave (k,e). Loads batched up-front (independent), then ballot-prefix.
__global__ __launch_bounds__(1024) void scan_kernel(const int* __restrict__ eidx,
                                                    int* __restrict__ toklist,
                                                    int* __restrict__ tokpos,
                                                    int* __restrict__ counts) {
  int t = threadIdx.x;
  int wid = t >> 6, lane = t & 63;
  int k = wid >> 3, e = wid & 7;
  int z = wid;
  int mye[64];
#pragma unroll
  for (int c = 0; c < 64; c++) mye[c] = eidx[(c * 64 + lane) * 2 + k];
  int base = 0;
#pragma unroll 4
  for (int c = 0; c < 64; c++) {
    int n = c * 64 + lane;
    bool pred = (mye[c] == e);
    unsigned long long mask = __ballot(pred);
    if (pred) {
      int pos = base + __popcll(mask & ((1ull << lane) - 1ull));
      if (pos < CAP) {
        toklist[z * CAPP + pos] = n;
        tokpos[k * N_TOK + n] = z * CAPP + pos;
      } else {
        tokpos[k * N_TOK + n] = -1;
      }
    }
    base += __popcll(mask);
  }
  if (lane == 0) counts[z] = (base < CAP) ? base : CAP;
}

// -------------------- GEMM1 + fused SwiGLU --------------------
// Tile: 128 tokens x 128 act cols (256 B-rows: h1 + h2). 4 waves 2x2, wave=64x64.
// global_load_lds staging; XOR swizzle applied on the GLOBAL address so the LDS
// side keeps the rigid base+lane*16 mapping. Grid flattened: XCD x <- expert x.
__global__ __launch_bounds__(256, 2) void gemm1_kernel(const _Float16* __restrict__ xh,
                                                       const _Float16* __restrict__ w1t,
                                                       const int* __restrict__ toklist,
                                                       const int* __restrict__ counts,
                                                       _Float16* __restrict__ act) {
  int i = blockIdx.x;
  int xcd = i & 7, j = i >> 3;       // 1280 blocks -> 160 per xcd
  int m = j % 5, ii = j / 5;         // ii<32: k = ii&1, n = ii>>1
  int k = ii & 1, n = ii >> 1;
  int e = xcd, z = k * 8 + e;
  int count = counts[z];
  int m0 = m * 128;
  if (m0 >= count) return;
  int n0 = n * 128;

  __shared__ _Float16 As[128 * 32];   // 8 KB, phys: row*32 + physUnit*8 halves
  __shared__ _Float16 Bs[256 * 32];   // 16 KB; rows 0..127 h1-cols, 128..255 h2-cols
  __shared__ int toks[128];

  int t = threadIdx.x;
  if (t < 128) {
    int r = m0 + t;
    toks[t] = (r < count) ? toklist[z * CAPP + r] : N_TOK;  // pad -> zero row
  }
  __syncthreads();

  int lane = t & 63, w = t >> 6;
  int l4 = lane >> 2, lu = lane & 3;

  // staging pointers. A: wave w covers rows [32w,32w+32) in 2 sweeps of 16 rows.
  const _Float16* ag[2]; _Float16* al[2];
#pragma unroll
  for (int s = 0; s < 2; s++) {
    int row = w * 32 + s * 16 + l4;
    int u = lu ^ ((row >> 1) & 3);
    ag[s] = xh + (long)toks[row] * DDIM + u * 8;
    al[s] = As + row * 32 + lu * 8;
  }
  // B: wave w covers rows [64w,64w+64) in 4 sweeps.
  const _Float16* bg[4]; _Float16* bl[4];
#pragma unroll
  for (int s = 0; s < 4; s++) {
    int rb = w * 64 + s * 16 + l4;
    int u = lu ^ ((rb >> 1) & 3);
    int gr = (rb < 128) ? (n0 + rb) : (2048 + n0 + (rb - 128));
    bg[s] = w1t + ((long)e * 4096 + gr) * DDIM + u * 8;
    bl[s] = Bs + rb * 32 + lu * 8;
  }

  int q = lane >> 4, m16 = lane & 15;
  int wm = w & 1, wn = w >> 1;

  f4 zero4 = {0.f, 0.f, 0.f, 0.f};
  f4 acc[4][4][2];
#pragma unroll
  for (int rt = 0; rt < 4; rt++)
#pragma unroll
    for (int ct = 0; ct < 4; ct++) { acc[rt][ct][0] = zero4; acc[rt][ct][1] = zero4; }

  for (int kk = 0; kk < DDIM; kk += 32) {
    __syncthreads();  // previous iter's readers done
#pragma unroll
    for (int s = 0; s < 2; s++) { gld16(ag[s], al[s]); ag[s] += 32; }
#pragma unroll
    for (int s = 0; s < 4; s++) { gld16(bg[s], bl[s]); bg[s] += 32; }
    asm volatile("s_waitcnt vmcnt(0)" ::: "memory");
    __syncthreads();

    half8 af[4], bf[4][2];
#pragma unroll
    for (int rt = 0; rt < 4; rt++) {
      int row = wm * 64 + rt * 16 + m16;
      af[rt] = *(const half8*)(As + row * 32 + (q ^ ((row >> 1) & 3)) * 8);
    }
#pragma unroll
    for (int ct = 0; ct < 4; ct++) {
      int c = wn * 64 + ct * 16 + m16;
      int sw = (q ^ ((c >> 1) & 3)) * 8;       // (c+128)>>1 has same &3
      bf[ct][0] = *(const half8*)(Bs + c * 32 + sw);
      bf[ct][1] = *(const half8*)(Bs + (128 + c) * 32 + sw);
    }
#pragma unroll
    for (int rt = 0; rt < 4; rt++)
#pragma unroll
      for (int ct = 0; ct < 4; ct++) {
        acc[rt][ct][0] = __builtin_amdgcn_mfma_f32_16x16x32_f16(af[rt], bf[ct][0], acc[rt][ct][0], 0, 0, 0);
        acc[rt][ct][1] = __builtin_amdgcn_mfma_f32_16x16x32_f16(af[rt], bf[ct][1], acc[rt][ct][1], 0, 0, 0);
      }
  }

  long ab = (long)z * CAPP * HDIM;
#pragma unroll
  for (int rt = 0; rt < 4; rt++)
#pragma unroll
    for (int ct = 0; ct < 4; ct++)
#pragma unroll
      for (int r = 0; r < 4; r++) {
        int row = m0 + wm * 64 + rt * 16 + q * 4 + r;  // C/D: row = quad*4 + reg
        int col = n0 + wn * 64 + ct * 16 + m16;        //      col = lane&15
        float h1 = acc[rt][ct][0][r], h2 = acc[rt][ct][1][r];
        float s = h2 / (1.f + __expf(-h2));
        act[ab + (long)row * HDIM + col] = (_Float16)(h1 * s);
      }
}

// -------------------- GEMM2 --------------------
// Tile 128 x 128, K=2048. Same staging structure. XCD x <- expert x.
__global__ __launch_bounds__(256, 2) void gemm2_kernel(const _Float16* __restrict__ act,
                                                       const _Float16* __restrict__ w2t,
                                                       const int* __restrict__ counts,
                                                       float* __restrict__ ybuf) {
  int i = blockIdx.x;
  int xcd = i & 7, j = i >> 3;       // 480 blocks -> 60 per xcd
  int m = j % 5, t2 = j / 5;         // t2<12: k = t2&1, n = t2>>1
  int k = t2 & 1, n = t2 >> 1;
  int e = xcd, z = k * 8 + e;
  int count = counts[z];
  int m0 = m * 128;
  if (m0 >= count) return;
  int n0 = n * 128;

  __shared__ _Float16 As[128 * 32];
  __shared__ _Float16 Bs[128 * 32];

  int t = threadIdx.x;
  int lane = t & 63, w = t >> 6;
  int l4 = lane >> 2, lu = lane & 3;

  const _Float16* ag[2]; _Float16* al[2];
#pragma unroll
  for (int s = 0; s < 2; s++) {
    int row = w * 32 + s * 16 + l4;
    int u = lu ^ ((row >> 1) & 3);
    ag[s] = act + ((long)z * CAPP + m0 + row) * HDIM + u * 8;
    al[s] = As + row * 32 + lu * 8;
  }
  const _Float16* bg[2]; _Float16* bl[2];
#pragma unroll
  for (int s = 0; s < 2; s++) {
    int rb = w * 32 + s * 16 + l4;
    int u = lu ^ ((rb >> 1) & 3);
    bg[s] = w2t + ((long)e * DDIM + n0 + rb) * HDIM + u * 8;
    bl[s] = Bs + rb * 32 + lu * 8;
  }

  int q = lane >> 4, m16 = lane & 15;
  int wm = w & 1, wn = w >> 1;

  f4 zero4 = {0.f, 0.f, 0.f, 0.f};
  f4 acc[4][4];
#pragma unroll
  for (int rt = 0; rt < 4; rt++)
#pragma unroll
    for (int ct = 0; ct < 4; ct++) acc[rt][ct] = zero4;

  for (int kk = 0; kk < HDIM; kk += 32) {
    __syncthreads();
#pragma unroll
    for (int s = 0; s < 2; s++) { gld16(ag[s], al[s]); ag[s] += 32; }
#pragma unroll
    for (int s = 0; s < 2; s++) { gld16(bg[s], bl[s]); bg[s] += 32; }
    asm volatile("s_waitcnt vmcnt(0)" ::: "memory");
    __syncthreads();

    half8 af[4], bf[4];
#pragma unroll
    for (int rt = 0; rt < 4; rt++) {
      int row = wm * 64 + rt * 16 + m16;
      af[rt] = *(const half8*)(As + row * 32 + (q ^ ((row >> 1) & 3)) * 8);
    }
#pragma unroll
    for (int ct = 0; ct < 4; ct++) {
      int c = wn * 64 + ct * 16 + m16;
      bf[ct] = *(const half8*)(Bs + c * 32 + (q ^ ((c >> 1) & 3)) * 8);
    }
#pragma unroll
    for (int rt = 0; rt < 4; rt++)
#pragma unroll
      for (int ct = 0; ct < 4; ct++)
        acc[rt][ct] = __builtin_amdgcn_mfma_f32_16x16x32_f16(af[rt], bf[ct], acc[rt][ct], 0, 0, 0);
  }

  long yb = (long)z * CAPP * DDIM;
#pragma unroll
  for (int rt = 0; rt < 4; rt++)
#pragma unroll
    for (int ct = 0; ct < 4; ct++)
#pragma unroll
      for (int r = 0; r < 4; r++) {
        int row = m0 + wm * 64 + rt * 16 + q * 4 + r;
        int col = n0 + wn * 64 + ct * 16 + m16;
        ybuf[yb + (long)row * DDIM + col] = acc[rt][ct][r];
      }
}

// -------------------- gather --------------------
__global__ __launch_bounds__(256) void gather_kernel(const float* __restrict__ ybuf,
                                                     const int* __restrict__ tokpos,
                                                     const float* __restrict__ wts,
                                                     float* __restrict__ out) {
  int gid = blockIdx.x * 256 + threadIdx.x;  // < 4096*192
  int row = gid / 192, seg = gid % 192;
  f4 o = {0.f, 0.f, 0.f, 0.f};
#pragma unroll
  for (int k = 0; k < 2; k++) {
    int p = tokpos[k * N_TOK + row];
    if (p >= 0) {
      float wv = wts[row * 2 + k];
      f4 y = *(const f4*)(ybuf + (long)p * DDIM + seg * 4);
      o[0] += wv * y[0]; o[1] += wv * y[1]; o[2] += wv * y[2]; o[3] += wv * y[3];
    }
  }
  *(f4*)(out + (long)row * DDIM + seg * 4) = o;
}

// -------------------- launch --------------------

extern "C" void kernel_launch(void* const* d_in, const int* in_sizes, int n_in,
                              void* d_out, int out_size, void* d_ws, size_t ws_size,
                              hipStream_t stream) {
  const float* x  = (const float*)d_in[0];
  const float* Wg = (const float*)d_in[1];
  const float* W1 = (const float*)d_in[2];
  const float* W2 = (const float*)d_in[3];
  float* out = (float*)d_out;
  char* ws = (char*)d_ws;

  _Float16* xh   = (_Float16*)(ws + XH_OFF);
  _Float16* w1t  = (_Float16*)(ws + W1T_OFF);
  _Float16* w2t  = (_Float16*)(ws + W2T_OFF);
  _Float16* actb = (_Float16*)(ws + ACT_OFF);
  float* ybuf    = (float*)(ws + YBUF_OFF);
  int* eidx      = (int*)(ws + EIDX_OFF);
  float* wts     = (float*)(ws + WTS_OFF);
  int* toklist   = (int*)(ws + TOKL_OFF);
  int* tokpos    = (int*)(ws + TOKP_OFF);
  int* counts    = (int*)(ws + CNT_OFF);

  cvt_x_kernel<<<3073, 256, 0, stream>>>(x, xh);
  cvt_tr_kernel<<<dim3(24, 128, 8), 256, 0, stream>>>(W1, w1t, 768, 4096);
  cvt_tr_kernel<<<dim3(64, 24, 8), 256, 0, stream>>>(W2, w2t, 2048, 768);
  router_kernel<<<1024, 256, 0, stream>>>(x, Wg, eidx, wts);
  scan_kernel<<<1, 1024, 0, stream>>>(eidx, toklist, tokpos, counts);
  gemm1_kernel<<<1280, 256, 0, stream>>>(xh, w1t, toklist, counts, actb);
  gemm2_kernel<<<480, 256, 0, stream>>>(actb, w2t, counts, ybuf);
  gather_kernel<<<3072, 256, 0, stream>>>(ybuf, tokpos, wts, out);
}